// Round 1
// baseline (1204.693 us; speedup 1.0000x reference)
//
#include <hip/hip_runtime.h>
#include <hip/hip_bf16.h>
#include <stdint.h>

#define H_DIM  2048
#define IM_DIM 1024
#define E_NUM  16
#define TOPK   8
#define IS_DIM 2048
#define SCALE_F 2.5f

// fallback-path tile params (round-1 kernels)
#define BM 128
#define BN 128
#define BK 32
#define LDSP 40

typedef __attribute__((ext_vector_type(8))) short   short8;
typedef __attribute__((ext_vector_type(8))) __bf16  bf16x8;
typedef __attribute__((ext_vector_type(4))) float   float4v;
typedef unsigned short ushort_t;

// async global->LDS, 16B per lane; LDS dest = wave-uniform base + lane*16
#define GLOAD_LDS16(gp, lp) \
    __builtin_amdgcn_global_load_lds((__attribute__((address_space(1))) void*)(gp), \
                                     (__attribute__((address_space(3))) void*)(lp), 16, 0, 0)

// raw barrier (no implicit vmcnt/lgkmcnt drain) + counted vmcnt. "memory"
// clobbers stop the compiler from moving LDS/global ops across them.
#define BAR()    asm volatile("s_barrier" ::: "memory")
#define VMCNT(n) asm volatile("s_waitcnt vmcnt(" #n ")" ::: "memory")

static __device__ __forceinline__ ushort_t f2bf(float x) {
    union { float f; uint32_t u; } v; v.f = x;
    uint32_t r = v.u + 0x7fffu + ((v.u >> 16) & 1u);  // RNE
    return (ushort_t)(r >> 16);
}

// ---------------- zero out ----------------
__global__ void zero4_kernel(float4* __restrict__ p, int n4) {
    int i = blockIdx.x * blockDim.x + threadIdx.x;
    if (i < n4) p[i] = make_float4(0.f, 0.f, 0.f, 0.f);
}

// ---------------- cast h (fp32 -> bf16) ----------------
__global__ void cast_h_kernel(const float* __restrict__ h, ushort_t* __restrict__ hb, int n4) {
    int i = blockIdx.x * blockDim.x + threadIdx.x;
    if (i < n4) {
        float4 v = ((const float4*)h)[i];
        ushort4 o;
        o.x = f2bf(v.x); o.y = f2bf(v.y); o.z = f2bf(v.z); o.w = f2bf(v.w);
        ((ushort4*)hb)[i] = o;
    }
}

// ---------------- router: sigmoid + top-8 -> dense comb[T,E] ----------------
__global__ void router_kernel(const float* __restrict__ h, const float* __restrict__ gw,
                              float* __restrict__ comb, int T) {
    int t = blockIdx.x;
    int l = threadIdx.x;
    const float* hr = h + (size_t)t * H_DIM;
    __shared__ float logits[E_NUM];
    for (int e = 0; e < E_NUM; e++) {
        const float* g = gw + e * H_DIM;
        float p = 0.f;
        #pragma unroll 8
        for (int j = l; j < H_DIM; j += 64) p += hr[j] * g[j];
        #pragma unroll
        for (int off = 32; off > 0; off >>= 1) p += __shfl_down(p, off);
        if (l == 0) logits[e] = p;
    }
    __syncthreads();
    if (l == 0) {
        float sig[E_NUM]; bool sel[E_NUM];
        #pragma unroll
        for (int e = 0; e < E_NUM; e++) { sig[e] = 1.f / (1.f + expf(-logits[e])); sel[e] = false; }
        #pragma unroll
        for (int k = 0; k < TOPK; k++) {
            int bi = 0; float bv = -1.f;
            #pragma unroll
            for (int e = 0; e < E_NUM; e++)
                if (!sel[e] && sig[e] > bv) { bv = sig[e]; bi = e; }
            sel[bi] = true;
        }
        float s = 0.f;
        #pragma unroll
        for (int e = 0; e < E_NUM; e++) if (sel[e]) s += sig[e];
        float inv = SCALE_F / (s + 1e-6f);
        #pragma unroll
        for (int e = 0; e < E_NUM; e++)
            comb[(size_t)t * E_NUM + e] = sel[e] ? sig[e] * inv : 0.f;
    }
}

// ---------------- transpose+convert: fp32 [z][K][N-slab] -> bf16 [z][N][K] ----------------
__global__ __launch_bounds__(256)
void transpose_cvt_kernel(const float* __restrict__ src, ushort_t* __restrict__ dst,
                          int K, int N, size_t sStride, size_t dStride)
{
    __shared__ float tile[64 * 65];
    int z = blockIdx.z;
    const float* S = src + (size_t)z * sStride;
    ushort_t* D = dst + (size_t)z * dStride;
    int k0 = blockIdx.x * 64, n0 = blockIdx.y * 64;
    int tid = threadIdx.x;
    int tr = tid >> 4, tc = (tid & 15) * 4;
    #pragma unroll
    for (int p = 0; p < 4; p++) {
        int r = tr + 16 * p;
        float4 v = *(const float4*)&S[(size_t)(k0 + r) * N + n0 + tc];
        tile[(tc + 0) * 65 + r] = v.x;
        tile[(tc + 1) * 65 + r] = v.y;
        tile[(tc + 2) * 65 + r] = v.z;
        tile[(tc + 3) * 65 + r] = v.w;
    }
    __syncthreads();
    #pragma unroll
    for (int p = 0; p < 4; p++) {
        int n = tr + 16 * p;
        ushort4 o;
        o.x = f2bf(tile[n * 65 + tc + 0]);
        o.y = f2bf(tile[n * 65 + tc + 1]);
        o.z = f2bf(tile[n * 65 + tc + 2]);
        o.w = f2bf(tile[n * 65 + tc + 3]);
        *(ushort4*)&D[(size_t)(n0 + n) * K + k0 + tc] = o;
    }
}

// =====================================================================================
// 8-phase-style counted-vmcnt GEMMs (T2 swizzle + T3/T4 pipeline + T5 setprio)
//
// LDS layout: [row][64] bf16, but the 16B granule within a row is stored at
// physical slot (logical_slot ^ (row&7)). global_load_lds writes linearly, so
// the *global source* address is pre-permuted with the same involution
// (lslot = (lane&7) ^ (lane>>3)), and reads apply the XOR on the slot index.
// Staging partition: every quarter-slab is staged only by waves that read it,
// so per-wave vmcnt(6) + s_barrier proves a tile is fully landed for all of
// its readers (loads for tile t are issued during tile t-1 => 1-tile slack).
// =====================================================================================

// ---------- GEMM1: C[z] = silu(A@G[z]^T) * (A@U[z]^T) * comb, bf16 out ----------
// tile 256M x 128N, BK=64, 8 waves (2M x 4N: each wave 128x32 of gate AND up)
__global__ __launch_bounds__(512, 1)
void gemm1_8p(const ushort_t* __restrict__ A,      // [T][H]
              const ushort_t* __restrict__ G0,     // [18][IM][H]
              const ushort_t* __restrict__ U0,     // [18][IM][H]
              ushort_t* __restrict__ C0,           // [18][T][IM]
              const float* __restrict__ comb, int T)
{
    __shared__ ushort_t As[2][256 * 64];   // 64 KiB
    __shared__ ushort_t Gs[2][128 * 64];   // 32 KiB
    __shared__ ushort_t Us[2][128 * 64];   // 32 KiB

    const int z   = blockIdx.z;
    const int t0  = blockIdx.x * 256;
    const int n0  = blockIdx.y * 128;
    const int tid = threadIdx.x;
    const int lane = tid & 63, wid = tid >> 6;
    const int wm = (wid >> 2) * 128;       // 0 / 128
    const int wn = (wid & 3) * 32;         // 0..96
    const int quad = lane >> 4, l15 = lane & 15;
    const int sw = l15 & 7;                // read-side row XOR key

    const int lrow8 = lane >> 3;           // 0..7 (row within 8-row load slab)
    const int lslot = (lane & 7) ^ lrow8;  // inverse-swizzled source 16B slot

    const ushort_t* G = G0 + (size_t)z * IM_DIM * H_DIM;
    const ushort_t* U = U0 + (size_t)z * IM_DIM * H_DIM;
    ushort_t*       C = C0 + (size_t)z * T * IM_DIM;

    // staging slabs (stagers == readers):
    // A: 32-row quarter of this wave's A-half.  G/U: 16-row slab of this wave's N-quarter.
    const int aq0 = wm + (wid & 3) * 32;
    const int bq0 = (wid & 3) * 32 + (wid >> 2) * 16;
    const ushort_t* aG = A + (size_t)(t0 + aq0 + lrow8) * H_DIM + lslot * 8;
    const ushort_t* gG = G + (size_t)(n0 + bq0 + lrow8) * H_DIM + lslot * 8;
    const ushort_t* uG = U + (size_t)(n0 + bq0 + lrow8) * H_DIM + lslot * 8;

#define G1_ISSUE_A(bb, ko) do { \
    GLOAD_LDS16(aG + (ko),               &As[bb][(aq0 + 0) * 64]);  \
    GLOAD_LDS16(aG + (ko) + 8 * H_DIM,   &As[bb][(aq0 + 8) * 64]);  \
    GLOAD_LDS16(aG + (ko) + 16 * H_DIM,  &As[bb][(aq0 + 16) * 64]); \
    GLOAD_LDS16(aG + (ko) + 24 * H_DIM,  &As[bb][(aq0 + 24) * 64]); \
} while (0)
#define G1_ISSUE_G(bb, ko) do { \
    GLOAD_LDS16(gG + (ko),               &Gs[bb][(bq0 + 0) * 64]);  \
    GLOAD_LDS16(gG + (ko) + 8 * H_DIM,   &Gs[bb][(bq0 + 8) * 64]);  \
} while (0)
#define G1_ISSUE_U(bb, ko) do { \
    GLOAD_LDS16(uG + (ko),               &Us[bb][(bq0 + 0) * 64]);  \
    GLOAD_LDS16(uG + (ko) + 8 * H_DIM,   &Us[bb][(bq0 + 8) * 64]);  \
} while (0)

    float4v accg[8][2], accu[8][2];
    #pragma unroll
    for (int i = 0; i < 8; ++i)
        #pragma unroll
        for (int j = 0; j < 2; ++j) {
            accg[i][j] = (float4v){0.f, 0.f, 0.f, 0.f};
            accu[i][j] = (float4v){0.f, 0.f, 0.f, 0.f};
        }

    // prologue: tile 0 (8 loads/thread)
    G1_ISSUE_A(0, 0); G1_ISSUE_G(0, 0); G1_ISSUE_U(0, 0);

    const int NT = H_DIM / 64;             // 32 K-tiles
    for (int t = 0; t < NT; ++t) {
        const int b  = t & 1;
        const int ko = (t + 1) * 64;
        if (t + 1 < NT) {
            G1_ISSUE_A(b ^ 1, ko);         // 4 loads for t+1
            G1_ISSUE_G(b ^ 1, ko);         // 2 loads for t+1
            VMCNT(6);                      // retain only the 6 just issued -> tile t landed
        } else {
            VMCNT(0);
        }
        BAR();

        bf16x8 a_[4][2], g_[2][2], u_[2][2];
        // ---- phase 0: gate, i = 0..3 ----
        #pragma unroll
        for (int i = 0; i < 4; ++i) {
            const int r = wm + i * 16 + l15;
            #pragma unroll
            for (int kk = 0; kk < 2; ++kk)
                a_[i][kk] = *(const bf16x8*)&As[b][r * 64 + (((kk * 4 + quad) ^ sw) << 3)];
        }
        #pragma unroll
        for (int j = 0; j < 2; ++j) {
            const int r = wn + j * 16 + l15;
            #pragma unroll
            for (int kk = 0; kk < 2; ++kk)
                g_[j][kk] = *(const bf16x8*)&Gs[b][r * 64 + (((kk * 4 + quad) ^ sw) << 3)];
        }
        __builtin_amdgcn_s_setprio(1);
        #pragma unroll
        for (int i = 0; i < 4; ++i)
            #pragma unroll
            for (int j = 0; j < 2; ++j)
                #pragma unroll
                for (int kk = 0; kk < 2; ++kk)
                    accg[i][j] = __builtin_amdgcn_mfma_f32_16x16x32_bf16(a_[i][kk], g_[j][kk], accg[i][j], 0, 0, 0);
        __builtin_amdgcn_s_setprio(0);
        BAR();

        // ---- phase 1: up, i = 0..3 ----
        if (t + 1 < NT) G1_ISSUE_U(b ^ 1, ko);   // last 2 loads for t+1
        #pragma unroll
        for (int j = 0; j < 2; ++j) {
            const int r = wn + j * 16 + l15;
            #pragma unroll
            for (int kk = 0; kk < 2; ++kk)
                u_[j][kk] = *(const bf16x8*)&Us[b][r * 64 + (((kk * 4 + quad) ^ sw) << 3)];
        }
        __builtin_amdgcn_s_setprio(1);
        #pragma unroll
        for (int i = 0; i < 4; ++i)
            #pragma unroll
            for (int j = 0; j < 2; ++j)
                #pragma unroll
                for (int kk = 0; kk < 2; ++kk)
                    accu[i][j] = __builtin_amdgcn_mfma_f32_16x16x32_bf16(a_[i][kk], u_[j][kk], accu[i][j], 0, 0, 0);
        __builtin_amdgcn_s_setprio(0);
        BAR();

        // ---- phase 2: gate, i = 4..7 ----
        #pragma unroll
        for (int i = 0; i < 4; ++i) {
            const int r = wm + (i + 4) * 16 + l15;
            #pragma unroll
            for (int kk = 0; kk < 2; ++kk)
                a_[i][kk] = *(const bf16x8*)&As[b][r * 64 + (((kk * 4 + quad) ^ sw) << 3)];
        }
        __builtin_amdgcn_s_setprio(1);
        #pragma unroll
        for (int i = 0; i < 4; ++i)
            #pragma unroll
            for (int j = 0; j < 2; ++j)
                #pragma unroll
                for (int kk = 0; kk < 2; ++kk)
                    accg[i + 4][j] = __builtin_amdgcn_mfma_f32_16x16x32_bf16(a_[i][kk], g_[j][kk], accg[i + 4][j], 0, 0, 0);
        __builtin_amdgcn_s_setprio(0);
        BAR();

        // ---- phase 3: up, i = 4..7 (pure register phase) ----
        __builtin_amdgcn_s_setprio(1);
        #pragma unroll
        for (int i = 0; i < 4; ++i)
            #pragma unroll
            for (int j = 0; j < 2; ++j)
                #pragma unroll
                for (int kk = 0; kk < 2; ++kk)
                    accu[i + 4][j] = __builtin_amdgcn_mfma_f32_16x16x32_bf16(a_[i][kk], u_[j][kk], accu[i + 4][j], 0, 0, 0);
        __builtin_amdgcn_s_setprio(0);
        // no barrier: next boundary's issue targets buf b, whose last reads
        // were in phase 2 (already fenced by phase-2's barrier).
    }

    // epilogue: fused SwiGLU + comb scale (z>=16 are shared-expert segs, sc=1)
    #pragma unroll
    for (int i = 0; i < 8; ++i) {
        #pragma unroll
        for (int r = 0; r < 4; ++r) {
            const int tr = t0 + wm + i * 16 + quad * 4 + r;
            const float sc = (z < E_NUM) ? comb[(size_t)tr * E_NUM + z] : 1.f;
            #pragma unroll
            for (int j = 0; j < 2; ++j) {
                const float g = accg[i][j][r], u = accu[i][j][r];
                const float v = (g / (1.f + __expf(-g))) * u * sc;
                C[(size_t)tr * IM_DIM + (n0 + wn + j * 16 + l15)] = f2bf(v);
            }
        }
    }
#undef G1_ISSUE_A
#undef G1_ISSUE_G
#undef G1_ISSUE_U
}

// ---------- GEMM2: Out += sum_seg A[seg] @ B[seg]^T (atomic, fp32 out) ----------
// tile 256M x 128N, BK=64, 8 waves (4M x 2N: each wave 64x64)
__global__ __launch_bounds__(512, 1)
void gemm2_8p(const ushort_t* __restrict__ A0,    // [18][T][IM]
              const ushort_t* __restrict__ B0,    // [18][H][IM]
              float* __restrict__ Out, int T, int nseg)
{
    __shared__ ushort_t As[2][256 * 64];   // 64 KiB
    __shared__ ushort_t Bs[2][128 * 64];   // 32 KiB

    const int z   = blockIdx.z;
    const int t0  = blockIdx.x * 256;
    const int n0  = blockIdx.y * 128;
    const int tid = threadIdx.x;
    const int lane = tid & 63, wid = tid >> 6;
    const int wm = (wid >> 1) * 64;
    const int wn = (wid & 1) * 64;
    const int quad = lane >> 4, l15 = lane & 15;
    const int sw = l15 & 7;
    const int lrow8 = lane >> 3;
    const int lslot = (lane & 7) ^ lrow8;

    const int aq0 = (wid >> 1) * 64 + (wid & 1) * 32;   // 32-row quarter (stagers==readers)
    const int bq0 = (wid & 1) * 64 + (wid >> 1) * 16;   // 16-row slab of this wave's B-half
    const ushort_t* aG = A0 + (size_t)(t0 + aq0 + lrow8) * IM_DIM + lslot * 8;
    const ushort_t* bG = B0 + (size_t)(n0 + bq0 + lrow8) * IM_DIM + lslot * 8;
    const size_t segA = (size_t)T * IM_DIM;
    const size_t segB = (size_t)H_DIM * IM_DIM;

#define G2_ISSUE(bb, tt) do { \
    const int    s_  = z * nseg + ((tt) >> 4); \
    const size_t ao_ = (size_t)s_ * segA + ((tt) & 15) * 64; \
    const size_t bo_ = (size_t)s_ * segB + ((tt) & 15) * 64; \
    GLOAD_LDS16(aG + ao_,                &As[bb][(aq0 + 0) * 64]);  \
    GLOAD_LDS16(aG + ao_ + 8 * IM_DIM,   &As[bb][(aq0 + 8) * 64]);  \
    GLOAD_LDS16(aG + ao_ + 16 * IM_DIM,  &As[bb][(aq0 + 16) * 64]); \
    GLOAD_LDS16(aG + ao_ + 24 * IM_DIM,  &As[bb][(aq0 + 24) * 64]); \
    GLOAD_LDS16(bG + bo_,                &Bs[bb][(bq0 + 0) * 64]);  \
    GLOAD_LDS16(bG + bo_ + 8 * IM_DIM,   &Bs[bb][(bq0 + 8) * 64]);  \
} while (0)

    float4v acc[4][4];
    #pragma unroll
    for (int i = 0; i < 4; ++i)
        #pragma unroll
        for (int j = 0; j < 4; ++j) acc[i][j] = (float4v){0.f, 0.f, 0.f, 0.f};

    G2_ISSUE(0, 0);
    const int nTT = nseg * (IM_DIM / 64);
    for (int tt = 0; tt < nTT; ++tt) {
        const int b = tt & 1;
        if (tt + 1 < nTT) { G2_ISSUE(b ^ 1, tt + 1); VMCNT(6); }
        else              { VMCNT(0); }
        BAR();

        bf16x8 a_[4][2], b_[4][2];
        // ---- phase 0: j = 0..1 ----
        #pragma unroll
        for (int i = 0; i < 4; ++i) {
            const int r = wm + i * 16 + l15;
            #pragma unroll
            for (int kk = 0; kk < 2; ++kk)
                a_[i][kk] = *(const bf16x8*)&As[b][r * 64 + (((kk * 4 + quad) ^ sw) << 3)];
        }
        #pragma unroll
        for (int j = 0; j < 2; ++j) {
            const int r = wn + j * 16 + l15;
            #pragma unroll
            for (int kk = 0; kk < 2; ++kk)
                b_[j][kk] = *(const bf16x8*)&Bs[b][r * 64 + (((kk * 4 + quad) ^ sw) << 3)];
        }
        __builtin_amdgcn_s_setprio(1);
        #pragma unroll
        for (int i = 0; i < 4; ++i)
            #pragma unroll
            for (int j = 0; j < 2; ++j)
                #pragma unroll
                for (int kk = 0; kk < 2; ++kk)
                    acc[i][j] = __builtin_amdgcn_mfma_f32_16x16x32_bf16(a_[i][kk], b_[j][kk], acc[i][j], 0, 0, 0);
        __builtin_amdgcn_s_setprio(0);
        BAR();

        // ---- phase 1: j = 2..3 ----
        #pragma unroll
        for (int j = 0; j < 2; ++j) {
            const int r = wn + (j + 2) * 16 + l15;
            #pragma unroll
            for (int kk = 0; kk < 2; ++kk)
                b_[j + 2][kk] = *(const bf16x8*)&Bs[b][r * 64 + (((kk * 4 + quad) ^ sw) << 3)];
        }
        __builtin_amdgcn_s_setprio(1);
        #pragma unroll
        for (int i = 0; i < 4; ++i)
            #pragma unroll
            for (int j = 2; j < 4; ++j)
                #pragma unroll
                for (int kk = 0; kk < 2; ++kk)
                    acc[i][j] = __builtin_amdgcn_mfma_f32_16x16x32_bf16(a_[i][kk], b_[j][kk], acc[i][j], 0, 0, 0);
        __builtin_amdgcn_s_setprio(0);
        BAR();
    }

    #pragma unroll
    for (int i = 0; i < 4; ++i)
        #pragma unroll
        for (int r = 0; r < 4; ++r) {
            const int tr = t0 + wm + i * 16 + quad * 4 + r;
            #pragma unroll
            for (int j = 0; j < 4; ++j)
                atomicAdd(&Out[(size_t)tr * H_DIM + n0 + wn + j * 16 + l15], acc[i][j][r]);
        }
#undef G2_ISSUE
}

// ================= FALLBACK PATH (round-1 kernels, ws-lean) ==========================

__global__ __launch_bounds__(256)
void gemm1_kernel(const ushort_t* __restrict__ A, int lda,
                  const float* __restrict__ Bg0, const float* __restrict__ Bu0,
                  size_t bSeg, int ldb,
                  ushort_t* __restrict__ C0, size_t cSeg, int ldc,
                  const float* __restrict__ comb, int Kdim)
{
    __shared__ ushort_t Als[BM * LDSP];
    __shared__ ushort_t Bgs[BN * LDSP];
    __shared__ ushort_t Bus[BN * LDSP];

    int z = blockIdx.z;
    const float* Bg = Bg0 + (size_t)z * bSeg;
    const float* Bu = Bu0 + (size_t)z * bSeg;
    ushort_t* C = C0 + (size_t)z * cSeg;

    int t0 = blockIdx.x * BM;
    int n0 = blockIdx.y * BN;
    int tid = threadIdx.x;
    int lane = tid & 63, wid = tid >> 6;
    int wm = (wid & 1) * 64, wn = (wid >> 1) * 64;
    int quad = lane >> 4, l15 = lane & 15;

    float4v accg[4][4], accu[4][4];
    #pragma unroll
    for (int i = 0; i < 4; i++)
        #pragma unroll
        for (int j = 0; j < 4; j++) {
            accg[i][j] = (float4v){0.f, 0.f, 0.f, 0.f};
            accu[i][j] = (float4v){0.f, 0.f, 0.f, 0.f};
        }

    int a_r  = tid >> 2, a_oc = tid & 3;
    int b_ko = (tid >> 4) & 3;
    int b_n  = 2 * ((tid & 15) + ((tid >> 6) << 4));

    for (int k0 = 0; k0 < Kdim; k0 += BK) {
        __syncthreads();
        {
            const ushort_t* s0 = A + (size_t)(t0 + a_r) * lda + k0 + a_oc * 8;
            *(short8*)&Als[a_r * LDSP + a_oc * 8] = *(const short8*)s0;
            const ushort_t* s1 = A + (size_t)(t0 + a_r + 64) * lda + k0 + a_oc * 8;
            *(short8*)&Als[(a_r + 64) * LDSP + a_oc * 8] = *(const short8*)s1;
        }
        {
            short8 g0, g1, u0, u1;
            #pragma unroll
            for (int j = 0; j < 8; j++) {
                size_t roff = (size_t)(k0 + b_ko * 8 + j) * ldb + n0 + b_n;
                float2 vg = *(const float2*)&Bg[roff];
                float2 vu = *(const float2*)&Bu[roff];
                g0[j] = (short)f2bf(vg.x); g1[j] = (short)f2bf(vg.y);
                u0[j] = (short)f2bf(vu.x); u1[j] = (short)f2bf(vu.y);
            }
            *(short8*)&Bgs[b_n * LDSP + b_ko * 8]       = g0;
            *(short8*)&Bgs[(b_n + 1) * LDSP + b_ko * 8] = g1;
            *(short8*)&Bus[b_n * LDSP + b_ko * 8]       = u0;
            *(short8*)&Bus[(b_n + 1) * LDSP + b_ko * 8] = u1;
        }
        __syncthreads();

        bf16x8 af[4], bg[4], bu[4];
        #pragma unroll
        for (int i = 0; i < 4; i++)
            af[i] = *(const bf16x8*)&Als[(wm + i * 16 + l15) * LDSP + quad * 8];
        #pragma unroll
        for (int j = 0; j < 4; j++) {
            bg[j] = *(const bf16x8*)&Bgs[(wn + j * 16 + l15) * LDSP + quad * 8];
            bu[j] = *(const bf16x8*)&Bus[(wn + j * 16 + l15) * LDSP + quad * 8];
        }
        #pragma unroll
        for (int i = 0; i < 4; i++)
            #pragma unroll
            for (int j = 0; j < 4; j++) {
                accg[i][j] = __builtin_amdgcn_mfma_f32_16x16x32_bf16(af[i], bg[j], accg[i][j], 0, 0, 0);
                accu[i][j] = __builtin_amdgcn_mfma_f32_16x16x32_bf16(af[i], bu[j], accu[i][j], 0, 0, 0);
            }
    }

    #pragma unroll
    for (int i = 0; i < 4; i++) {
        #pragma unroll
        for (int r = 0; r < 4; r++) {
            int t = t0 + wm + i * 16 + quad * 4 + r;
            float sc = comb ? comb[(size_t)t * E_NUM + z] : 1.f;
            #pragma unroll
            for (int j = 0; j < 4; j++) {
                float g = accg[i][j][r], u = accu[i][j][r];
                float sg = g / (1.f + __expf(-g));
                float v = sg * u * sc;
                int c = n0 + wn + j * 16 + l15;
                C[(size_t)t * ldc + c] = f2bf(v);
            }
        }
    }
}

__global__ __launch_bounds__(256)
void gemm2_kernel(const ushort_t* __restrict__ A0, size_t aSeg, int lda,
                  const float* __restrict__ B0, size_t bSeg, int ldb,
                  float* __restrict__ Out, int N,
                  int nseg, int Kper, int accum)
{
    __shared__ ushort_t Als[BM * LDSP];
    __shared__ ushort_t Bls[BN * LDSP];

    int t0 = blockIdx.x * BM;
    int n0 = blockIdx.y * BN;
    int tid = threadIdx.x;
    int lane = tid & 63, wid = tid >> 6;
    int wm = (wid & 1) * 64, wn = (wid >> 1) * 64;
    int quad = lane >> 4, l15 = lane & 15;

    float4v acc[4][4];
    #pragma unroll
    for (int i = 0; i < 4; i++)
        #pragma unroll
        for (int j = 0; j < 4; j++) acc[i][j] = (float4v){0.f, 0.f, 0.f, 0.f};

    int a_r  = tid >> 2, a_oc = tid & 3;
    int b_ko = (tid >> 4) & 3;
    int b_n  = 2 * ((tid & 15) + ((tid >> 6) << 4));

    for (int seg = 0; seg < nseg; seg++) {
        const ushort_t* A = A0 + (size_t)seg * aSeg;
        const float*    B = B0 + (size_t)seg * bSeg;
        for (int k0 = 0; k0 < Kper; k0 += BK) {
            __syncthreads();
            {
                const ushort_t* s0 = A + (size_t)(t0 + a_r) * lda + k0 + a_oc * 8;
                *(short8*)&Als[a_r * LDSP + a_oc * 8] = *(const short8*)s0;
                const ushort_t* s1 = A + (size_t)(t0 + a_r + 64) * lda + k0 + a_oc * 8;
                *(short8*)&Als[(a_r + 64) * LDSP + a_oc * 8] = *(const short8*)s1;
            }
            {
                short8 r0, r1;
                #pragma unroll
                for (int j = 0; j < 8; j++) {
                    size_t roff = (size_t)(k0 + b_ko * 8 + j) * ldb + n0 + b_n;
                    float2 v = *(const float2*)&B[roff];
                    r0[j] = (short)f2bf(v.x); r1[j] = (short)f2bf(v.y);
                }
                *(short8*)&Bls[b_n * LDSP + b_ko * 8]       = r0;
                *(short8*)&Bls[(b_n + 1) * LDSP + b_ko * 8] = r1;
            }
            __syncthreads();

            bf16x8 af[4], bf[4];
            #pragma unroll
            for (int i = 0; i < 4; i++)
                af[i] = *(const bf16x8*)&Als[(wm + i * 16 + l15) * LDSP + quad * 8];
            #pragma unroll
            for (int j = 0; j < 4; j++)
                bf[j] = *(const bf16x8*)&Bls[(wn + j * 16 + l15) * LDSP + quad * 8];
            #pragma unroll
            for (int i = 0; i < 4; i++)
                #pragma unroll
                for (int j = 0; j < 4; j++)
                    acc[i][j] = __builtin_amdgcn_mfma_f32_16x16x32_bf16(af[i], bf[j], acc[i][j], 0, 0, 0);
        }
    }

    #pragma unroll
    for (int i = 0; i < 4; i++) {
        #pragma unroll
        for (int r = 0; r < 4; r++) {
            int t = t0 + wm + i * 16 + quad * 4 + r;
            #pragma unroll
            for (int j = 0; j < 4; j++) {
                int c = n0 + wn + j * 16 + l15;
                size_t idx = (size_t)t * N + c;
                float v = acc[i][j][r];
                if (accum) Out[idx] += v; else Out[idx] = v;
            }
        }
    }
}

// =====================================================================================

extern "C" void kernel_launch(void* const* d_in, const int* in_sizes, int n_in,
                              void* d_out, int out_size, void* d_ws, size_t ws_size,
                              hipStream_t stream) {
    const float* h      = (const float*)d_in[0];
    const float* gate_w = (const float*)d_in[1];
    const float* Wg     = (const float*)d_in[2];
    const float* Wu     = (const float*)d_in[3];
    const float* Wd     = (const float*)d_in[4];
    const float* sWg    = (const float*)d_in[5];
    const float* sWu    = (const float*)d_in[6];
    const float* sWd    = (const float*)d_in[7];
    float* out = (float*)d_out;
    int T = in_sizes[0] / H_DIM;
    (void)n_in; (void)out_size;

    const int NSEG = E_NUM + 2;   // 16 routed + 2 shared pseudo-experts

    char* ws = (char*)d_ws;
    size_t off = 0;
    auto alloc = [&](size_t bytes) -> void* {
        void* p = ws + off;
        off = (off + bytes + 255) & ~(size_t)255;
        return p;
    };
    ushort_t* h_bf = (ushort_t*)alloc((size_t)T * H_DIM * 2);
    float*    comb = (float*)   alloc((size_t)T * E_NUM * 4);
    ushort_t* act  = (ushort_t*)alloc((size_t)NSEG * T * IM_DIM * 2);        // 72 MB
    ushort_t* bufG = (ushort_t*)alloc((size_t)NSEG * IM_DIM * H_DIM * 2);    // 72 MB
    ushort_t* bufU = (ushort_t*)alloc((size_t)NSEG * IM_DIM * H_DIM * 2);    // 72 MB
    size_t need = off;

    int n4 = T * H_DIM / 4;
    cast_h_kernel<<<(n4 + 255) / 256, 256, 0, stream>>>(h, h_bf, n4);
    router_kernel<<<T, 64, 0, stream>>>(h, gate_w, comb, T);

    if (ws_size >= need) {
        // ---- fast path: merged 18-segment weights + counted-vmcnt pipelined GEMMs ----
        zero4_kernel<<<(n4 + 255) / 256, 256, 0, stream>>>((float4*)out, n4);

        // gate weights: routed [E][H][IM] -> [E][IM][H]; shared [H][IS] -> 2x[IM][H]
        transpose_cvt_kernel<<<dim3(H_DIM / 64, IM_DIM / 64, E_NUM), 256, 0, stream>>>(
            Wg, bufG, H_DIM, IM_DIM, (size_t)H_DIM * IM_DIM, (size_t)IM_DIM * H_DIM);
        transpose_cvt_kernel<<<dim3(H_DIM / 64, IM_DIM / 64, 2), 256, 0, stream>>>(
            sWg, bufG + (size_t)E_NUM * IM_DIM * H_DIM, H_DIM, IS_DIM,
            (size_t)IM_DIM, (size_t)IM_DIM * H_DIM);
        // up weights
        transpose_cvt_kernel<<<dim3(H_DIM / 64, IM_DIM / 64, E_NUM), 256, 0, stream>>>(
            Wu, bufU, H_DIM, IM_DIM, (size_t)H_DIM * IM_DIM, (size_t)IM_DIM * H_DIM);
        transpose_cvt_kernel<<<dim3(H_DIM / 64, IM_DIM / 64, 2), 256, 0, stream>>>(
            sWu, bufU + (size_t)E_NUM * IM_DIM * H_DIM, H_DIM, IS_DIM,
            (size_t)IM_DIM, (size_t)IM_DIM * H_DIM);

        gemm1_8p<<<dim3(T / 256, IM_DIM / 128, NSEG), 512, 0, stream>>>(
            h_bf, bufG, bufU, act, comb, T);

        // down weights into bufG (free after gemm1):
        // routed [E][IM][H] -> [E][H][IM]; shared [IS][H] -> 2x[H][IM]
        transpose_cvt_kernel<<<dim3(IM_DIM / 64, H_DIM / 64, E_NUM), 256, 0, stream>>>(
            Wd, bufG, IM_DIM, H_DIM, (size_t)IM_DIM * H_DIM, (size_t)H_DIM * IM_DIM);
        transpose_cvt_kernel<<<dim3(IM_DIM / 64, H_DIM / 64, 2), 256, 0, stream>>>(
            sWd, bufG + (size_t)E_NUM * H_DIM * IM_DIM, IM_DIM, H_DIM,
            (size_t)IM_DIM * H_DIM, (size_t)H_DIM * IM_DIM);

        // 6 z-groups x 3 segments = 18; 8*16*6 = 768 blocks = 3 full CU waves
        gemm2_8p<<<dim3(T / 256, H_DIM / 128, 6), 512, 0, stream>>>(
            act, bufG, out, T, 3);
    } else {
        // ---- fallback: round-1 path (~80 MB ws) ----
        ushort_t* act_r = act;
        ushort_t* act_s = act + (size_t)E_NUM * T * IM_DIM;
        gemm1_kernel<<<dim3(T / BM, IS_DIM / BN, 1), 256, 0, stream>>>(
            h_bf, H_DIM, sWg, sWu, 0, IS_DIM, act_s, 0, IS_DIM, nullptr, H_DIM);
        gemm1_kernel<<<dim3(T / BM, IM_DIM / BN, E_NUM), 256, 0, stream>>>(
            h_bf, H_DIM, Wg, Wu, (size_t)H_DIM * IM_DIM, IM_DIM,
            act_r, (size_t)T * IM_DIM, IM_DIM, comb, H_DIM);
        gemm2_kernel<<<dim3(T / BM, H_DIM / BN, 1), 256, 0, stream>>>(
            act_s, 0, IS_DIM, sWd, 0, H_DIM, out, H_DIM, 1, IS_DIM, 0);
        gemm2_kernel<<<dim3(T / BM, H_DIM / BN, 1), 256, 0, stream>>>(
            act_r, (size_t)T * IM_DIM, IM_DIM, Wd, (size_t)IM_DIM * H_DIM, H_DIM,
            out, H_DIM, E_NUM, IM_DIM, 1);
    }
}